// Round 7
// baseline (205.383 us; speedup 1.0000x reference)
//
#include <hip/hip_runtime.h>
#include <cstdint>
#include <cstddef>

typedef unsigned short u16;
typedef unsigned int u32;
typedef __bf16 bf16x8 __attribute__((ext_vector_type(8)));
typedef float f32x4 __attribute__((ext_vector_type(4)));

// float -> bf16 (RNE), raw bits
__device__ __forceinline__ u16 f2bf(float f) {
    unsigned int x = __builtin_bit_cast(unsigned int, f);
    x += 0x7FFFu + ((x >> 16) & 1u);
    return (u16)(x >> 16);
}

__device__ __forceinline__ bf16x8 ldfrag(const u16* p) {
    bf16x8 r;
    __builtin_memcpy(&r, (const u16*)__builtin_assume_aligned(p, 16), 16);
    return r;
}

__device__ __forceinline__ int4 ldg16(const u16* p) {
    int4 r;
    __builtin_memcpy(&r, (const u16*)__builtin_assume_aligned(p, 16), 16);
    return r;
}

// async global->LDS, 16B per lane; lds dest = wave-uniform base + lane*16
__device__ __forceinline__ void async16(u16* lds, const u16* g) {
    __builtin_amdgcn_global_load_lds(
        (const __attribute__((address_space(1))) void*)g,
        (__attribute__((address_space(3))) void*)lds,
        16, 0, 0);
}

// ---------------------------------------------------------------- cvt x->bf16
__global__ __launch_bounds__(256) void cvt_bf16(const float* __restrict__ in,
                                                u16* __restrict__ out, int n) {
    int i = (blockIdx.x * 256 + threadIdx.x) * 4;
    if (i >= n) return;
    float4 v = *reinterpret_cast<const float4*>(in + i);
    union { u16 e[4]; unsigned long long u; } w;
    w.e[0] = f2bf(v.x); w.e[1] = f2bf(v.y); w.e[2] = f2bf(v.z); w.e[3] = f2bf(v.w);
    *reinterpret_cast<unsigned long long*>(out + i) = w.u;
}

// ------------------------------------------------- W [768][2304] -> Wt bf16 [2304][768]
__global__ __launch_bounds__(256) void wt_transpose(const float* __restrict__ W,
                                                    u16* __restrict__ Wt) {
    const int R = 768, Ccols = 2304;
    __shared__ float tile[32][33];
    const int bx = blockIdx.x * 32;
    const int by = blockIdx.y * 32;
    const int tx = threadIdx.x & 31, ty = threadIdx.x >> 5;
    #pragma unroll
    for (int i = 0; i < 32; i += 8)
        tile[ty + i][tx] = W[(size_t)(by + ty + i) * Ccols + bx + tx];
    __syncthreads();
    #pragma unroll
    for (int i = 0; i < 32; i += 8)
        Wt[(size_t)(bx + ty + i) * R + by + tx] = f2bf(tile[tx][ty + i]);
}

// ---------------------------------------------------------------- QKV GEMM
// (unchanged from r6 -- in-buffer pipeline; counters readable this round)
__global__ __launch_bounds__(256) void qkv_gemm(const u16* __restrict__ A,
                                                const u16* __restrict__ Bt,   // [N][K]
                                                const float* __restrict__ bias,
                                                u16* __restrict__ C) {
    const int N = 2304, K = 768;
    __shared__ __align__(16) u16 sA[128 * 64];   // 16 KB, chunk ^= row&7
    __shared__ __align__(16) u16 sB[128 * 64];   // 16 KB
    const int t = threadIdx.x;
    const int wave = t >> 6, lane = t & 63;
    const int quad = lane >> 4, l16 = lane & 15;
    const int wr = wave >> 1, wc = wave & 1;

    const int bid = blockIdx.x;
    const int xcd = bid & 7;
    const int idx = bid >> 3;                   // 0..143
    const int m0 = (xcd * 8 + idx / 18) * 128;  // m-tile 0..63, 8 per XCD
    const int n0 = (idx % 18) * 128;            // n-tile 0..17

    const int srow_base = wave * 8 + (lane >> 3);
    const int schunk = lane & 7;
    const int swz = (lane >> 3) & 7;
    const int dch = schunk ^ swz;

    auto stage = [&](int k0) {
        #pragma unroll
        for (int j = 0; j < 4; ++j) {
            const int row = j * 32 + srow_base;
            async16(sA + j * 2048 + wave * 512, A + (size_t)(m0 + row) * K + k0 + dch * 8);
            async16(sB + j * 2048 + wave * 512, Bt + (size_t)(n0 + row) * K + k0 + dch * 8);
        }
    };

    f32x4 acc[4][4] = {};

    stage(0);
    for (int k0 = 0; k0 < K; k0 += 64) {
        asm volatile("s_waitcnt vmcnt(0)" ::: "memory");
        __builtin_amdgcn_s_barrier();
        asm volatile("" ::: "memory");

        bf16x8 af[4][2], bfr[4][2];
        const int rsw = l16 & 7;
        #pragma unroll
        for (int i = 0; i < 4; ++i)
            #pragma unroll
            for (int h = 0; h < 2; ++h) {
                af[i][h] = ldfrag(sA + (wr * 64 + i * 16 + l16) * 64 + (((h * 4 + quad) ^ rsw) << 3));
                bfr[i][h] = ldfrag(sB + (wc * 64 + i * 16 + l16) * 64 + (((h * 4 + quad) ^ rsw) << 3));
            }

        asm volatile("s_waitcnt lgkmcnt(0)" ::: "memory");
        __builtin_amdgcn_s_barrier();
        asm volatile("" ::: "memory");

        if (k0 + 64 < K) stage(k0 + 64);   // HBM latency hides under MFMA below

        #pragma unroll
        for (int h = 0; h < 2; ++h)
            #pragma unroll
            for (int i = 0; i < 4; ++i)
                #pragma unroll
                for (int j = 0; j < 4; ++j)
                    acc[i][j] = __builtin_amdgcn_mfma_f32_16x16x32_bf16(af[i][h], bfr[j][h], acc[i][j], 0, 0, 0);
    }

    #pragma unroll
    for (int i = 0; i < 4; ++i)
        #pragma unroll
        for (int j = 0; j < 4; ++j) {
            const int col = n0 + wc * 64 + j * 16 + l16;
            const float bc = bias[col];
            const float scale = (col < 768) ? 0.125f : 1.0f;
            #pragma unroll
            for (int r = 0; r < 4; ++r) {
                const int row = m0 + wr * 64 + i * 16 + quad * 4 + r;
                C[(size_t)row * N + col] = f2bf((acc[i][j][r] + bc) * scale);
            }
        }
}

// ---------------------------------------------------------------- attention
// KVBLK=128: iteration count is THE cost driver (measured law: ~753 ns*CU per
// block-iteration, invariant to occupancy/work-per-iter across r1-r6). Paired
// q-tiles (qa, qb=31-qa) per block, 768 blocks; per iter one 128-token KV
// tile = sub-tiles j=2it, 2it+1. Wave owns two 16-token K slices in regs;
// Q in regs; V^T double-buffered in LDS; lgkm-only barriers (2 per iter).
// Total block-iters: 9.6K (was 18.8K @KVBLK=64).
__global__ __launch_bounds__(256, 2) void attn_kernel(const u16* __restrict__ qkv,
                                                      float* __restrict__ out) {
    const int T = 2048, C3 = 2304, Cc = 768, Dh = 64;

    // XCD-grouped decode: xcd = bid&7, 6 (b,h) groups per XCD, qa = idx/6
    // ascending -> qb descending: longest blocks dispatch first.
    const int bid = blockIdx.x;
    const int xcd = bid & 7;
    const int idx = bid >> 3;          // 0..95
    const int qa = idx / 6;            // 0..15
    const int qb = 31 - qa;
    const int hb = xcd * 6 + (idx % 6);
    const int h = hb % 12, b = hb / 12;
    const int nit = qb / 2 + 1;        // 128-token KV tiles

    const int t = threadIdx.x;
    const int wave = t >> 6, lane = t & 63;
    const int quad = lane >> 4, l16 = lane & 15;

    __shared__ __align__(16) u32 sVt[2][64 * 68];   // 34.8 KB, [d][tokpair], pad 68
    __shared__ __align__(16) u16 sP[128 * 136];     // 34.8 KB, [q row][tok], pad 136

    const u16* qbase = qkv + (size_t)b * T * C3 + (size_t)h * Dh;
    const u16* kbase = qbase + Cc;
    const u16* vbase = qbase + 2 * Cc;

    // Q B-frags: qf[cg][half]; cg<4 = tile a rows, cg>=4 = tile b rows
    bf16x8 qf[8][2];
    #pragma unroll
    for (int cg = 0; cg < 8; ++cg) {
        const int qrow = ((cg < 4) ? qa * 64 : (qb * 64 - 64)) + cg * 16 + l16;
        const u16* p = qbase + (size_t)qrow * C3 + quad * 8;
        qf[cg][0] = ldfrag(p);
        qf[cg][1] = ldfrag(p + 32);
    }

    f32x4 oacc[2][4] = {};

    // V staging: thread handles tokpair=lane (tokens 2*lane, 2*lane+1) and
    // d-range wave*16..+15 -> 4x ldg16, 16x ds_write_b32 (2-way bank, free).
    auto loadV = [&](int it2, int4* r) {
        const u16* vp = vbase + (size_t)(it2 * 128 + 2 * lane) * C3 + wave * 16;
        r[0] = ldg16(vp);
        r[1] = ldg16(vp + 8);
        r[2] = ldg16(vp + C3);
        r[3] = ldg16(vp + C3 + 8);
    };
    auto writeV = [&](int bi, const int4* r) {
        union { int4 v; u16 e[8]; } u0, u1, u2, u3;
        u0.v = r[0]; u1.v = r[1]; u2.v = r[2]; u3.v = r[3];
        #pragma unroll
        for (int i = 0; i < 8; ++i) {
            sVt[bi][(wave * 16 + i) * 68 + lane]     = (u32)u0.e[i] | ((u32)u2.e[i] << 16);
            sVt[bi][(wave * 16 + 8 + i) * 68 + lane] = (u32)u1.e[i] | ((u32)u3.e[i] << 16);
        }
    };
    // K A-frags for both 64-token sub-slices of the 128-tile
    auto ldgK = [&](int it2, bf16x8 k[2][2]) {
        #pragma unroll
        for (int s = 0; s < 2; ++s) {
            const u16* kp = kbase + (size_t)(it2 * 128 + s * 64 + wave * 16 + l16) * C3 + quad * 8;
            k[s][0] = ldfrag(kp);
            k[s][1] = ldfrag(kp + 32);
        }
    };

    bf16x8 kc[2][2], kn[2][2];
    int4 vc[4], vn[4];

    // prologue: V(0) -> LDS buf0, V(1) -> regs, K(0) -> regs
    {
        int4 a[4];
        loadV(0, a);
        ldgK(0, kc);
        writeV(0, a);
    }
    loadV(1, vc);
    #pragma unroll
    for (int i = 0; i < 4; ++i) vn[i] = vc[i];
    __syncthreads();

    int buf = 0;
    for (int it = 0; it < nit; ++it) {
        const bool more  = (it + 1 < nit);
        const bool more2 = (it + 2 < nit);
        if (more2) loadV(it + 2, vn);          // 2-ahead V prefetch
        if (more)  ldgK(it + 1, kn);           // 1-ahead K prefetch

        // ---- QK over sub-tiles j = 2it, 2it+1 (uniform-branch causal gating)
        __builtin_amdgcn_s_setprio(1);
        #pragma unroll
        for (int cg = 0; cg < 8; ++cg) {
            const int qt = (cg < 4) ? qa : qb;
            u16* prow = sP + (((cg >> 2) * 64 + (cg & 3) * 16 + l16) * 136) + wave * 16 + quad * 4;
            #pragma unroll
            for (int s = 0; s < 2; ++s) {
                const int j = 2 * it + s;
                u16* dst = prow + s * 64;
                if (j <= qt) {
                    f32x4 sc = {};
                    sc = __builtin_amdgcn_mfma_f32_16x16x32_bf16(kc[s][0], qf[cg][0], sc, 0, 0, 0);
                    sc = __builtin_amdgcn_mfma_f32_16x16x32_bf16(kc[s][1], qf[cg][1], sc, 0, 0, 0);
                    u32 bits[4];
                    #pragma unroll
                    for (int r = 0; r < 4; ++r) {
                        float v = fmaxf(sc[r], 0.0f);
                        if (j == qt && (wave * 16 + quad * 4 + r > (cg & 3) * 16 + l16)) v = 0.0f;
                        bits[r] = __builtin_bit_cast(u32, v);
                    }
                    u32 pk[2];
                    pk[0] = (bits[1] & 0xFFFF0000u) | (bits[0] >> 16);
                    pk[1] = (bits[3] & 0xFFFF0000u) | (bits[2] >> 16);
                    __builtin_memcpy((u16*)__builtin_assume_aligned(dst, 8), pk, 8);
                } else if (j == qt + 1 || j == qt + 2) {
                    // first dead sub-tile per s-half: zero once; stays zero after
                    u32 z[2] = {0, 0};
                    __builtin_memcpy((u16*)__builtin_assume_aligned(dst, 8), z, 8);
                }
            }
        }
        __builtin_amdgcn_s_setprio(0);

        // ---- barrier 1 (lgkm-only): P visible; global prefetches in flight
        asm volatile("s_waitcnt lgkmcnt(0)" ::: "memory");
        __builtin_amdgcn_s_barrier();
        asm volatile("" ::: "memory");

        // ---- PV: O[g] += P[g rows] @ V^T over 128 tokens (kk = 4 chunks)
        const u16* sVb = (const u16*)&sVt[buf][0];
        __builtin_amdgcn_s_setprio(1);
        #pragma unroll
        for (int kk = 0; kk < 4; ++kk) {
            bf16x8 ap0 = ldfrag(sP + (wave * 16 + l16) * 136 + kk * 32 + quad * 8);
            bf16x8 ap1 = ldfrag(sP + (64 + wave * 16 + l16) * 136 + kk * 32 + quad * 8);
            #pragma unroll
            for (int dt = 0; dt < 4; ++dt) {
                bf16x8 bv = ldfrag(sVb + (dt * 16 + l16) * 136 + kk * 32 + quad * 8);
                oacc[0][dt] = __builtin_amdgcn_mfma_f32_16x16x32_bf16(ap0, bv, oacc[0][dt], 0, 0, 0);
                oacc[1][dt] = __builtin_amdgcn_mfma_f32_16x16x32_bf16(ap1, bv, oacc[1][dt], 0, 0, 0);
            }
        }
        __builtin_amdgcn_s_setprio(0);

        // writeV consumes vc = V(it+1), loaded 1.5 iterations ago
        if (more) writeV(buf ^ 1, vc);

        // ---- barrier 2 (lgkm-only): V(it+1) visible; sP safe to overwrite
        asm volatile("s_waitcnt lgkmcnt(0)" ::: "memory");
        __builtin_amdgcn_s_barrier();
        asm volatile("" ::: "memory");

        #pragma unroll
        for (int s = 0; s < 2; ++s) {
            kc[s][0] = kn[s][0]; kc[s][1] = kn[s][1];
        }
        #pragma unroll
        for (int i = 0; i < 4; ++i) vc[i] = vn[i];
        buf ^= 1;
    }

    // ---- write O (fp32, C/D layout): row m = quad*4+r, col = l16
    #pragma unroll
    for (int g = 0; g < 2; ++g)
        #pragma unroll
        for (int dt = 0; dt < 4; ++dt)
            #pragma unroll
            for (int r = 0; r < 4; ++r) {
                const int tok = (g == 0 ? qa * 64 : qb * 64) + wave * 16 + quad * 4 + r;
                const int c = h * Dh + dt * 16 + l16;
                out[((size_t)b * T + tok) * Cc + c] = oacc[g][dt][r];
            }
}

// ---------------------------------------------------------------- launch
extern "C" void kernel_launch(void* const* d_in, const int* in_sizes, int n_in,
                              void* d_out, int out_size, void* d_ws, size_t ws_size,
                              hipStream_t stream) {
    const float* x    = (const float*)d_in[0];   // [4,2048,768]
    const float* W    = (const float*)d_in[1];   // [768,2304]
    const float* bias = (const float*)d_in[2];   // [2304]
    float* out = (float*)d_out;                  // [4,2048,768]

    char* ws = (char*)d_ws;
    const size_t xb_bytes = (size_t)8192 * 768 * 2;
    const size_t wt_bytes = (size_t)2304 * 768 * 2;
    u16* xb  = (u16*)ws;
    u16* Wt  = (u16*)(ws + xb_bytes);
    u16* qkv = (u16*)(ws + xb_bytes + wt_bytes);

    cvt_bf16<<<6144, 256, 0, stream>>>(x, xb, 8192 * 768);
    wt_transpose<<<dim3(72, 24), 256, 0, stream>>>(W, Wt);
    qkv_gemm<<<1152, 256, 0, stream>>>(xb, Wt, bias, qkv);
    attn_kernel<<<768, 256, 0, stream>>>(qkv, out);
}

// Round 9
// 167.312 us; speedup vs baseline: 1.2275x; 1.2275x over previous
//
#include <hip/hip_runtime.h>
#include <cstdint>
#include <cstddef>

typedef unsigned short u16;
typedef unsigned int u32;
typedef __bf16 bf16x8 __attribute__((ext_vector_type(8)));
typedef float f32x4 __attribute__((ext_vector_type(4)));

// float -> bf16 (RNE), raw bits
__device__ __forceinline__ u16 f2bf(float f) {
    unsigned int x = __builtin_bit_cast(unsigned int, f);
    x += 0x7FFFu + ((x >> 16) & 1u);
    return (u16)(x >> 16);
}

__device__ __forceinline__ bf16x8 ldfrag(const u16* p) {
    bf16x8 r;
    __builtin_memcpy(&r, (const u16*)__builtin_assume_aligned(p, 16), 16);
    return r;
}

__device__ __forceinline__ int4 ldg16(const u16* p) {
    int4 r;
    __builtin_memcpy(&r, (const u16*)__builtin_assume_aligned(p, 16), 16);
    return r;
}

// async global->LDS, 16B per lane; lds dest = wave-uniform base + lane*16
__device__ __forceinline__ void async16(u16* lds, const u16* g) {
    __builtin_amdgcn_global_load_lds(
        (const __attribute__((address_space(1))) void*)g,
        (__attribute__((address_space(3))) void*)lds,
        16, 0, 0);
}

// ------------------------------------------------- prep: cvt x->bf16 + W transpose
// Merged into ONE dispatch (launch-overhead probe): blocks 0..6143 convert x,
// blocks 6144..7871 transpose W into Wt bf16.
__global__ __launch_bounds__(256) void prep(const float* __restrict__ x,
                                            u16* __restrict__ xb,
                                            const float* __restrict__ W,
                                            u16* __restrict__ Wt) {
    const int bid = blockIdx.x;
    if (bid < 6144) {
        // ---- cvt: 8192*768 floats, 4 per thread
        int i = (bid * 256 + threadIdx.x) * 4;
        float4 v = *reinterpret_cast<const float4*>(x + i);
        union { u16 e[4]; unsigned long long u; } w;
        w.e[0] = f2bf(v.x); w.e[1] = f2bf(v.y); w.e[2] = f2bf(v.z); w.e[3] = f2bf(v.w);
        *reinterpret_cast<unsigned long long*>(xb + i) = w.u;
    } else {
        // ---- W [768][2304] -> Wt bf16 [2304][768]
        const int R = 768, Ccols = 2304;
        __shared__ float tile[32][33];
        const int b2 = bid - 6144;               // 0..1727
        const int bx = (b2 % 72) * 32;
        const int by = (b2 / 72) * 32;
        const int tx = threadIdx.x & 31, ty = threadIdx.x >> 5;
        #pragma unroll
        for (int i = 0; i < 32; i += 8)
            tile[ty + i][tx] = W[(size_t)(by + ty + i) * Ccols + bx + tx];
        __syncthreads();
        #pragma unroll
        for (int i = 0; i < 32; i += 8)
            Wt[(size_t)(bx + ty + i) * R + by + tx] = f2bf(tile[tx][ty + i]);
    }
}

// ---------------------------------------------------------------- QKV GEMM
// C[M=8192][N=2304] = A[M][K=768] @ Wt^T + bias. BK=64, XOR swizzle.
// In-buffer pipeline: per K-step, [vmcnt0+bar] -> ds_read frags ->
// [lgkm0+bar] -> stage(t+1) into SAME buffer -> MFMA(t). Stage HBM latency
// covered by the 32-MFMA cluster. XCD-grouped 1D grid (1152).
__global__ __launch_bounds__(256) void qkv_gemm(const u16* __restrict__ A,
                                                const u16* __restrict__ Bt,   // [N][K]
                                                const float* __restrict__ bias,
                                                u16* __restrict__ C) {
    const int N = 2304, K = 768;
    __shared__ __align__(16) u16 sA[128 * 64];   // 16 KB, chunk ^= row&7
    __shared__ __align__(16) u16 sB[128 * 64];   // 16 KB
    const int t = threadIdx.x;
    const int wave = t >> 6, lane = t & 63;
    const int quad = lane >> 4, l16 = lane & 15;
    const int wr = wave >> 1, wc = wave & 1;

    const int bid = blockIdx.x;
    const int xcd = bid & 7;
    const int idx = bid >> 3;                   // 0..143
    const int m0 = (xcd * 8 + idx / 18) * 128;  // m-tile 0..63, 8 per XCD
    const int n0 = (idx % 18) * 128;            // n-tile 0..17

    const int srow_base = wave * 8 + (lane >> 3);
    const int schunk = lane & 7;
    const int swz = (lane >> 3) & 7;
    const int dch = schunk ^ swz;

    auto stage = [&](int k0) {
        #pragma unroll
        for (int j = 0; j < 4; ++j) {
            const int row = j * 32 + srow_base;
            async16(sA + j * 2048 + wave * 512, A + (size_t)(m0 + row) * K + k0 + dch * 8);
            async16(sB + j * 2048 + wave * 512, Bt + (size_t)(n0 + row) * K + k0 + dch * 8);
        }
    };

    f32x4 acc[4][4] = {};

    stage(0);
    for (int k0 = 0; k0 < K; k0 += 64) {
        asm volatile("s_waitcnt vmcnt(0)" ::: "memory");
        __builtin_amdgcn_s_barrier();
        asm volatile("" ::: "memory");

        bf16x8 af[4][2], bfr[4][2];
        const int rsw = l16 & 7;
        #pragma unroll
        for (int i = 0; i < 4; ++i)
            #pragma unroll
            for (int h = 0; h < 2; ++h) {
                af[i][h] = ldfrag(sA + (wr * 64 + i * 16 + l16) * 64 + (((h * 4 + quad) ^ rsw) << 3));
                bfr[i][h] = ldfrag(sB + (wc * 64 + i * 16 + l16) * 64 + (((h * 4 + quad) ^ rsw) << 3));
            }

        asm volatile("s_waitcnt lgkmcnt(0)" ::: "memory");
        __builtin_amdgcn_s_barrier();
        asm volatile("" ::: "memory");

        if (k0 + 64 < K) stage(k0 + 64);   // HBM latency hides under MFMA below

        #pragma unroll
        for (int h = 0; h < 2; ++h)
            #pragma unroll
            for (int i = 0; i < 4; ++i)
                #pragma unroll
                for (int j = 0; j < 4; ++j)
                    acc[i][j] = __builtin_amdgcn_mfma_f32_16x16x32_bf16(af[i][h], bfr[j][h], acc[i][j], 0, 0, 0);
    }

    #pragma unroll
    for (int i = 0; i < 4; ++i)
        #pragma unroll
        for (int j = 0; j < 4; ++j) {
            const int col = n0 + wc * 64 + j * 16 + l16;
            const float bc = bias[col];
            const float scale = (col < 768) ? 0.125f : 1.0f;
            #pragma unroll
            for (int r = 0; r < 4; ++r) {
                const int row = m0 + wr * 64 + i * 16 + quad * 4 + r;
                C[(size_t)row * N + col] = f2bf((acc[i][j][r] + bc) * scale);
            }
        }
}

// ---------------------------------------------------------------- attention
// REVERTED verbatim to the r5 version (measured 55.3 us): paired q-tiles
// (qa, qb=31-qa), KVBLK=64, 768 blocks, K+Q frags in regs (K 1-ahead, V
// 2-ahead prefetch), lgkm-only barriers, XCD-grouped (b,h). Model from
// r1-r7 data: kernel is SIMD issue-slot bound; this config minimizes
// (total block-iters) x (instructions per iter) among tested variants.
__global__ __launch_bounds__(256, 3) void attn_kernel(const u16* __restrict__ qkv,
                                                      float* __restrict__ out) {
    const int T = 2048, C3 = 2304, Cc = 768, Dh = 64;

    const int bid = blockIdx.x;
    const int xcd = bid & 7;
    const int idx = bid >> 3;
    const int hb = xcd * 6 + (idx % 6);
    const int qa = idx / 6;
    const int qb = 31 - qa;
    const int h = hb % 12, b = hb / 12;

    const int t = threadIdx.x;
    const int wave = t >> 6, lane = t & 63;
    const int quad = lane >> 4, l16 = lane & 15;

    __shared__ __align__(16) u32 sVt[2][64 * 36];   // 18 KB, [d][tokpair]
    __shared__ __align__(16) u16 sP[128 * 72];      // 18 KB

    const u16* qbase = qkv + (size_t)b * T * C3 + (size_t)h * Dh;
    const u16* kbase = qbase + Cc;
    const u16* vbase = qbase + 2 * Cc;

    bf16x8 qf[8][2];
    #pragma unroll
    for (int cg = 0; cg < 8; ++cg) {
        const int qrow = ((cg < 4) ? qa * 64 : (qb * 64 - 64)) + cg * 16 + l16;
        const u16* p = qbase + (size_t)qrow * C3 + quad * 8;
        qf[cg][0] = ldfrag(p);
        qf[cg][1] = ldfrag(p + 32);
    }

    f32x4 oacc[2][4] = {};

    const int tp = t & 31, dg = t >> 5;            // V staging

    auto loadV = [&](int it, int4& r0, int4& r1) {
        const u16* vp = vbase + (size_t)(it * 64 + 2 * tp) * C3 + dg * 8;
        r0 = ldg16(vp);
        r1 = ldg16(vp + C3);
    };
    auto ldgK = [&](int it, bf16x8& f0, bf16x8& f1) {
        const u16* kp = kbase + (size_t)(it * 64 + wave * 16 + l16) * C3 + quad * 8;
        f0 = ldfrag(kp);
        f1 = ldfrag(kp + 32);
    };
    auto writeV = [&](int bi, const int4& r0, const int4& r1) {
        union { int4 v; u16 e[8]; } ua, ub;
        ua.v = r0; ub.v = r1;
        #pragma unroll
        for (int i = 0; i < 8; ++i)
            sVt[bi][(dg * 8 + i) * 36 + tp] = (u32)ua.e[i] | ((u32)ub.e[i] << 16);
    };

    bf16x8 kc0, kc1, kn0, kn1;
    int4 vc0, vc1, vn0, vn1;

    {
        int4 a0, a1;
        loadV(0, a0, a1);
        ldgK(0, kc0, kc1);
        writeV(0, a0, a1);
    }
    loadV(1, vc0, vc1);
    vn0 = vc0; vn1 = vc1;
    __syncthreads();

    int buf = 0;
    for (int it = 0; it <= qb; ++it) {
        const bool more  = (it < qb);
        const bool more2 = (it + 1 < qb);
        if (more2) loadV(it + 2, vn0, vn1);        // 2-ahead V prefetch
        if (more)  ldgK(it + 1, kn0, kn1);         // 1-ahead K prefetch

        const bool act_a = (it <= qa);

        const int cg_lo = act_a ? 0 : 4;
        __builtin_amdgcn_s_setprio(1);
        #pragma unroll
        for (int cg = 7; cg >= 0; --cg) {           // b tiles first (always active)
            if (cg < cg_lo) break;
            f32x4 s = {};
            s = __builtin_amdgcn_mfma_f32_16x16x32_bf16(kc0, qf[cg][0], s, 0, 0, 0);
            s = __builtin_amdgcn_mfma_f32_16x16x32_bf16(kc1, qf[cg][1], s, 0, 0, 0);
            const bool diag = (cg < 4) ? (it == qa) : (it == qb);
            u32 bits[4];
            #pragma unroll
            for (int r = 0; r < 4; ++r) {
                float v = fmaxf(s[r], 0.0f);
                if (diag && (wave * 16 + quad * 4 + r > (cg & 3) * 16 + l16)) v = 0.0f;
                bits[r] = __builtin_bit_cast(u32, v);
            }
            u32 pk[2];
            pk[0] = (bits[1] & 0xFFFF0000u) | (bits[0] >> 16);
            pk[1] = (bits[3] & 0xFFFF0000u) | (bits[2] >> 16);
            __builtin_memcpy((u16*)__builtin_assume_aligned(
                                 sP + (cg * 16 + l16) * 72 + wave * 16 + quad * 4, 8),
                             pk, 8);
        }
        __builtin_amdgcn_s_setprio(0);

        asm volatile("s_waitcnt lgkmcnt(0)" ::: "memory");
        __builtin_amdgcn_s_barrier();
        asm volatile("" ::: "memory");

        const u16* sVb = (const u16*)sVt[buf];
        __builtin_amdgcn_s_setprio(1);
        #pragma unroll
        for (int kk = 0; kk < 2; ++kk) {
            bf16x8 ap1 = ldfrag(sP + (64 + wave * 16 + l16) * 72 + kk * 32 + quad * 8);
            bf16x8 ap0;
            if (act_a) ap0 = ldfrag(sP + (wave * 16 + l16) * 72 + kk * 32 + quad * 8);
            #pragma unroll
            for (int dt = 0; dt < 4; ++dt) {
                bf16x8 bv = ldfrag(sVb + (dt * 16 + l16) * 72 + kk * 32 + quad * 8);
                oacc[1][dt] = __builtin_amdgcn_mfma_f32_16x16x32_bf16(ap1, bv, oacc[1][dt], 0, 0, 0);
                if (act_a)
                    oacc[0][dt] = __builtin_amdgcn_mfma_f32_16x16x32_bf16(ap0, bv, oacc[0][dt], 0, 0, 0);
            }
        }
        __builtin_amdgcn_s_setprio(0);

        if (more) writeV(buf ^ 1, vc0, vc1);

        asm volatile("s_waitcnt lgkmcnt(0)" ::: "memory");
        __builtin_amdgcn_s_barrier();
        asm volatile("" ::: "memory");

        kc0 = kn0; kc1 = kn1;
        vc0 = vn0; vc1 = vn1;
        buf ^= 1;
    }

    #pragma unroll
    for (int g = 0; g < 2; ++g)
        #pragma unroll
        for (int dt = 0; dt < 4; ++dt)
            #pragma unroll
            for (int r = 0; r < 4; ++r) {
                const int tok = (g == 0 ? qa * 64 : qb * 64) + wave * 16 + quad * 4 + r;
                const int c = h * Dh + dt * 16 + l16;
                out[((size_t)b * T + tok) * Cc + c] = oacc[g][dt][r];
            }
}

// ---------------------------------------------------------------- launch
extern "C" void kernel_launch(void* const* d_in, const int* in_sizes, int n_in,
                              void* d_out, int out_size, void* d_ws, size_t ws_size,
                              hipStream_t stream) {
    const float* x    = (const float*)d_in[0];   // [4,2048,768]
    const float* W    = (const float*)d_in[1];   // [768,2304]
    const float* bias = (const float*)d_in[2];   // [2304]
    float* out = (float*)d_out;                  // [4,2048,768]

    char* ws = (char*)d_ws;
    const size_t xb_bytes = (size_t)8192 * 768 * 2;
    const size_t wt_bytes = (size_t)2304 * 768 * 2;
    u16* xb  = (u16*)ws;
    u16* Wt  = (u16*)(ws + xb_bytes);
    u16* qkv = (u16*)(ws + xb_bytes + wt_bytes);

    prep<<<7872, 256, 0, stream>>>(x, xb, W, Wt);
    qkv_gemm<<<1152, 256, 0, stream>>>(xb, Wt, bias, qkv);
    attn_kernel<<<768, 256, 0, stream>>>(qkv, out);
}